// Round 4
// baseline (1385.797 us; speedup 1.0000x reference)
//
#include <hip/hip_runtime.h>
#include <hip/hip_bf16.h>
#include <math.h>

// Problem constants (B=8, Q=4096, C=256, H=8, D=32, L=4, P=4)
// Levels: 128x128, 64x64, 32x32, 16x16
// Inputs: fp32 storage (proven R1->R2). Output: fp32 (theory B, this round's test).
// ws layout (bytes from d_ws), peak 53,084,416 B:
//   [0,4)       : int dtype flag (1 = inputs fp32, 0 = inputs bf16)
//   +256        : locs fp32 [B*Q][8][16][2]               (33,554,432 B)
//   +33,554,688 : attn bf16 [B*Q][8][16]                  ( 8,388,608 B)
//   +41,943,296 : vbuf bf16 [21760][256] (ONE batch, all levels) (11,141,120 B)
// pre-projection rows live in d_out as fp32; outproj RMWs in place (block-local).

__device__ __forceinline__ float bf2f(unsigned short u) {
    return __uint_as_float(((unsigned int)u) << 16);
}
__device__ __forceinline__ unsigned short f2bf(float f) {
    unsigned int x = __float_as_uint(f);
    unsigned int r = x + 0x7fffu + ((x >> 16) & 1u);
    return (unsigned short)(r >> 16);
}
__device__ __forceinline__ float ldg_(const void* p, long i, int isf) {
    return isf ? ((const float*)p)[i] : bf2f(((const unsigned short*)p)[i]);
}

// ---------------- K0: detect input dtype (fp32 viewed as bf16 -> huge exponents)
__global__ __launch_bounds__(256) void detect_kernel(
    const unsigned short* __restrict__ q,
    const unsigned short* __restrict__ f0,
    int* __restrict__ flag)
{
    const int t = threadIdx.x;
    int big = 0;
    for (int i = t; i < 8192; i += 256) {
        float a = bf2f(q[i]);
        float b = bf2f(f0[i]);
        if (fabsf(a) > 1e6f || fabsf(b) > 1e6f) big = 1;
    }
    unsigned long long m = __ballot(big != 0);
    __shared__ int s[4];
    if ((t & 63) == 0) s[t >> 6] = (m != 0ull) ? 1 : 0;
    __syncthreads();
    if (t == 0) flag[0] = (s[0] | s[1] | s[2] | s[3]);
}

// ---------------- K1: query projections -> tanh offsets -> pixel locs; softmax attn
__global__ __launch_bounds__(256) void qproj_kernel(
    const void* __restrict__ query,   // [B*Q,256]
    const void* __restrict__ refp,    // [B*Q,2]
    const void* __restrict__ W_off,   // [256,256] row-major (c, col)
    const void* __restrict__ b_off,   // [256]
    const void* __restrict__ W_attn,  // [256,128]
    const void* __restrict__ b_attn,  // [128]
    const int* __restrict__ flag,
    float* __restrict__ locs,             // [B*Q,8,16,2]
    unsigned short* __restrict__ attn)    // bf16 [B*Q,8,16]
{
    const int isf = *flag;
    __shared__ float q_lds[16][256];
    __shared__ float logit_lds[16][128];
    const int t = threadIdx.x;
    const int r0 = blockIdx.x * 16;

    for (int i = 0; i < 16; ++i)
        q_lds[i][t] = ldg_(query, (long)(r0 + i) * 256 + t, isf);
    __syncthreads();

    if (t < 128) {
        // offsets col = h*32 + l*8 + p*2 + xy; t = h*16 + l*4 + p -> cols 2t, 2t+1
        float acc0[16], acc1[16];
#pragma unroll
        for (int i = 0; i < 16; ++i) { acc0[i] = 0.f; acc1[i] = 0.f; }
        for (int c = 0; c < 256; c += 2) {
            const float w0x = ldg_(W_off, (long)(c + 0) * 256 + 2 * t, isf);
            const float w0y = ldg_(W_off, (long)(c + 0) * 256 + 2 * t + 1, isf);
            const float w1x = ldg_(W_off, (long)(c + 1) * 256 + 2 * t, isf);
            const float w1y = ldg_(W_off, (long)(c + 1) * 256 + 2 * t + 1, isf);
#pragma unroll
            for (int i = 0; i < 16; ++i) {
                const float q0 = q_lds[i][c], q1 = q_lds[i][c + 1];
                acc0[i] += q0 * w0x + q1 * w1x;
                acc1[i] += q0 * w0y + q1 * w1y;
            }
        }
        const float bx = ldg_(b_off, 2 * t, isf);
        const float by = ldg_(b_off, 2 * t + 1, isf);
        const int h = t >> 4, lp = t & 15, l = (t >> 2) & 3;
        const float scale = 2.0f * (float)(1 << l);
        const int Wl = 128 >> l;
        const float dim1 = (float)(Wl - 1);
#pragma unroll
        for (int i = 0; i < 16; ++i) {
            const int r = r0 + i;
            const float rx = ldg_(refp, (long)r * 2 + 0, isf);
            const float ry = ldg_(refp, (long)r * 2 + 1, isf);
            const float px = rx * dim1 + tanhf(acc0[i] + bx) * scale;
            const float py = ry * dim1 + tanhf(acc1[i] + by) * scale;
            float* lpp = locs + (((long)r * 8 + h) * 16 + lp) * 2;
            lpp[0] = px; lpp[1] = py;
        }
    } else {
        const int k = t - 128;  // attn col = h*16 + (l*4+p)
        float acc[16];
#pragma unroll
        for (int i = 0; i < 16; ++i) acc[i] = 0.f;
        for (int c = 0; c < 256; c += 2) {
            const float w0 = ldg_(W_attn, (long)(c + 0) * 128 + k, isf);
            const float w1 = ldg_(W_attn, (long)(c + 1) * 128 + k, isf);
#pragma unroll
            for (int i = 0; i < 16; ++i) {
                const float q0 = q_lds[i][c], q1 = q_lds[i][c + 1];
                acc[i] += q0 * w0 + q1 * w1;
            }
        }
        const float bb = ldg_(b_attn, k, isf);
#pragma unroll
        for (int i = 0; i < 16; ++i) logit_lds[i][k] = acc[i] + bb;
    }
    __syncthreads();

    if (t < 128) {  // softmax over 16 per (row, head)
        const int i = t >> 3;
        const int h = t & 7;
        float m = -1e30f;
#pragma unroll
        for (int k = 0; k < 16; ++k) m = fmaxf(m, logit_lds[i][h * 16 + k]);
        float e[16]; float s = 0.f;
#pragma unroll
        for (int k = 0; k < 16; ++k) { e[k] = __expf(logit_lds[i][h * 16 + k] - m); s += e[k]; }
        const float inv = 1.0f / s;
        const int r = r0 + i;
        unsigned short* ap = attn + ((long)r * 8 + h) * 16;
#pragma unroll
        for (int k = 0; k < 16; ++k) ap[k] = f2bf(e[k] * inv);
    }
}

// ---------------- K2: value projection for ONE batch, all 4 levels.
// vbuf[loff_l + s*256 + o] = sum_c feat[b][c][s] * Wv[o][c] + bv[o]
__device__ __forceinline__ void vproj_inner(float (&acc)[32], const float (*fs)[32],
                                            const float* w, int cc) {
#pragma unroll
    for (int j = 0; j < 8; ++j) {
        const int c = cc + j;
#pragma unroll
        for (int s4 = 0; s4 < 8; ++s4) {
            const float4 f4 = *(const float4*)&fs[c][s4 * 4];
            acc[s4 * 4 + 0] += w[j] * f4.x;
            acc[s4 * 4 + 1] += w[j] * f4.y;
            acc[s4 * 4 + 2] += w[j] * f4.z;
            acc[s4 * 4 + 3] += w[j] * f4.w;
        }
    }
}

__global__ __launch_bounds__(256) void vproj_kernel(
    const void* __restrict__ feat0,
    const void* __restrict__ feat1,
    const void* __restrict__ feat2,
    const void* __restrict__ feat3,
    const void* __restrict__ Wv0, const void* __restrict__ bv0,
    const void* __restrict__ Wv1, const void* __restrict__ bv1,
    const void* __restrict__ Wv2, const void* __restrict__ bv2,
    const void* __restrict__ Wv3, const void* __restrict__ bv3,
    const int* __restrict__ flag, int b,
    unsigned short* __restrict__ vbuf)
{
    const int isf = *flag;
    __shared__ float fs[256][32];
    const int blk = blockIdx.x;
    const void *feat, *Wv, *bv;
    int S; long voff; int til;
    if (blk < 512)       { til = blk;       feat = feat0; Wv = Wv0; bv = bv0; S = 16384; voff = 0; }
    else if (blk < 640)  { til = blk - 512; feat = feat1; Wv = Wv1; bv = bv1; S = 4096;  voff = 4194304; }
    else if (blk < 672)  { til = blk - 640; feat = feat2; Wv = Wv2; bv = bv2; S = 1024;  voff = 5242880; }
    else                 { til = blk - 672; feat = feat3; Wv = Wv3; bv = bv3; S = 256;   voff = 5505024; }
    const int s0 = til << 5;
    const int t = threadIdx.x;

    {   // stage feat tile [256 c][32 s]
        const long fb = (long)b * 256 * S + s0;
        for (int i = 0; i < 32; ++i) {
            const int e = i * 256 + t;
            const int c = e >> 5, s = e & 31;
            fs[c][s] = ldg_(feat, fb + (long)c * S + s, isf);
        }
    }
    __syncthreads();

    float acc[32];
    const float bias = ldg_(bv, t, isf);
#pragma unroll
    for (int i = 0; i < 32; ++i) acc[i] = bias;

    if (isf) {
        const float* wrow = (const float*)Wv + (long)t * 256;
        for (int cc = 0; cc < 256; cc += 8) {
            const float4 a4 = *(const float4*)(wrow + cc);
            const float4 b4 = *(const float4*)(wrow + cc + 4);
            float w[8] = {a4.x, a4.y, a4.z, a4.w, b4.x, b4.y, b4.z, b4.w};
            vproj_inner(acc, fs, w, cc);
        }
    } else {
        const unsigned short* wrow = (const unsigned short*)Wv + (long)t * 256;
        for (int cc = 0; cc < 256; cc += 8) {
            const uint4 wv = *(const uint4*)(wrow + cc);
            float w[8];
            w[0] = bf2f((unsigned short)wv.x); w[1] = bf2f((unsigned short)(wv.x >> 16));
            w[2] = bf2f((unsigned short)wv.y); w[3] = bf2f((unsigned short)(wv.y >> 16));
            w[4] = bf2f((unsigned short)wv.z); w[5] = bf2f((unsigned short)(wv.z >> 16));
            w[6] = bf2f((unsigned short)wv.w); w[7] = bf2f((unsigned short)(wv.w >> 16));
            vproj_inner(acc, fs, w, cc);
        }
    }

    unsigned short* vp = vbuf + voff + (long)s0 * 256 + t;
#pragma unroll
    for (int s = 0; s < 32; ++s) vp[(long)s * 256] = f2bf(acc[s]);
}

// ---------------- K3: bilinear sampling + attn-weighted accumulate for ONE batch.
// Writes pre[r*256 + h*32+d] as FP32 into d_out.
__global__ __launch_bounds__(256) void sample_kernel(
    const float* __restrict__ locs,
    const unsigned short* __restrict__ attn,   // bf16
    const unsigned short* __restrict__ vbuf,   // this batch's values
    int b,
    float* __restrict__ pre)                   // d_out, fp32
{
    const int r = b * 4096 + blockIdx.x;
    const int t = threadIdx.x;
    const int h = t >> 5, d = t & 31;
    const long loff[4] = {0, 4194304, 5242880, 5505024};

    const float* lpb = locs + ((long)r * 8 + h) * 32;
    const unsigned short* apb = attn + ((long)r * 8 + h) * 16;
    float o = 0.f;
#pragma unroll
    for (int l = 0; l < 4; ++l) {
        const int Wl = 128 >> l;
        const unsigned short* V = vbuf + loff[l] + h * 32 + d;
#pragma unroll
        for (int p = 0; p < 4; ++p) {
            const int k = l * 4 + p;
            const float px = lpb[k * 2], py = lpb[k * 2 + 1];
            const float a = bf2f(apb[k]);
            const float fx = floorf(px), fy = floorf(py);
            const int x0 = (int)fx, y0 = (int)fy;
            const int x1 = x0 + 1, y1 = y0 + 1;
            const float wx = px - fx, wy = py - fy;
            const bool vx0 = (x0 >= 0) && (x0 < Wl), vx1 = (x1 >= 0) && (x1 < Wl);
            const bool vy0 = (y0 >= 0) && (y0 < Wl), vy1 = (y1 >= 0) && (y1 < Wl);
            const int cx0 = min(max(x0, 0), Wl - 1), cx1 = min(max(x1, 0), Wl - 1);
            const int cy0 = min(max(y0, 0), Wl - 1), cy1 = min(max(y1, 0), Wl - 1);
            const float g00 = bf2f(V[(long)(cy0 * Wl + cx0) * 256]);
            const float g01 = bf2f(V[(long)(cy0 * Wl + cx1) * 256]);
            const float g10 = bf2f(V[(long)(cy1 * Wl + cx0) * 256]);
            const float g11 = bf2f(V[(long)(cy1 * Wl + cx1) * 256]);
            const float w00 = (1.f - wx) * (1.f - wy) * ((vx0 && vy0) ? 1.f : 0.f);
            const float w01 = wx * (1.f - wy) * ((vx1 && vy0) ? 1.f : 0.f);
            const float w10 = (1.f - wx) * wy * ((vx0 && vy1) ? 1.f : 0.f);
            const float w11 = wx * wy * ((vx1 && vy1) ? 1.f : 0.f);
            o += a * (g00 * w00 + g01 * w01 + g10 * w10 + g11 * w11);
        }
    }
    pre[(long)r * 256 + t] = o;
}

// ---------------- K4: output projection, in-place on d_out (block-local RMW), fp32
__global__ __launch_bounds__(256) void outproj_kernel(
    const void* __restrict__ W_out,  // [256,256] row-major (c, j)
    const void* __restrict__ b_out,  // [256]
    const int* __restrict__ flag,
    float* io)                       // d_out fp32: read pre rows, write out rows
{
    const int isf = *flag;
    __shared__ float x_lds[16][256];
    const int t = threadIdx.x;
    const int r0 = blockIdx.x * 16;
    for (int i = 0; i < 16; ++i)
        x_lds[i][t] = io[(long)(r0 + i) * 256 + t];
    __syncthreads();

    float acc[16];
#pragma unroll
    for (int i = 0; i < 16; ++i) acc[i] = 0.f;
    for (int c = 0; c < 256; c += 2) {
        const float w0 = ldg_(W_out, (long)(c + 0) * 256 + t, isf);
        const float w1 = ldg_(W_out, (long)(c + 1) * 256 + t, isf);
#pragma unroll
        for (int i = 0; i < 16; ++i) {
            const float q0 = x_lds[i][c], q1 = x_lds[i][c + 1];
            acc[i] += q0 * w0 + q1 * w1;
        }
    }
    const float bb = ldg_(b_out, t, isf);
#pragma unroll
    for (int i = 0; i < 16; ++i)
        io[(long)(r0 + i) * 256 + t] = acc[i] + bb;
}

extern "C" void kernel_launch(void* const* d_in, const int* in_sizes, int n_in,
                              void* d_out, int out_size, void* d_ws, size_t ws_size,
                              hipStream_t stream) {
    const void* query  = d_in[0];
    const void* refp   = d_in[1];
    const void* feat0  = d_in[2];
    const void* feat1  = d_in[3];
    const void* feat2  = d_in[4];
    const void* feat3  = d_in[5];
    const void* W_off  = d_in[6];
    const void* b_off  = d_in[7];
    const void* W_attn = d_in[8];
    const void* b_attn = d_in[9];
    const void* Wv0 = d_in[10]; const void* bv0 = d_in[11];
    const void* Wv1 = d_in[12]; const void* bv1 = d_in[13];
    const void* Wv2 = d_in[14]; const void* bv2 = d_in[15];
    const void* Wv3 = d_in[16]; const void* bv3 = d_in[17];
    const void* W_out = d_in[18]; const void* b_out = d_in[19];
    float* out = (float*)d_out;

    int* flag = (int*)d_ws;
    float* locs = (float*)((char*)d_ws + 256);
    unsigned short* attn = (unsigned short*)((char*)d_ws + 33554688);
    unsigned short* vbuf = (unsigned short*)((char*)d_ws + 41943296);

    detect_kernel<<<1, 256, 0, stream>>>((const unsigned short*)query,
                                         (const unsigned short*)feat0, flag);
    qproj_kernel<<<2048, 256, 0, stream>>>(query, refp, W_off, b_off, W_attn, b_attn,
                                           flag, locs, attn);
    for (int b = 0; b < 8; ++b) {
        vproj_kernel<<<680, 256, 0, stream>>>(feat0, feat1, feat2, feat3,
                                              Wv0, bv0, Wv1, bv1, Wv2, bv2, Wv3, bv3,
                                              flag, b, vbuf);
        sample_kernel<<<4096, 256, 0, stream>>>(locs, attn, vbuf, b, out);
    }
    outproj_kernel<<<2048, 256, 0, stream>>>(W_out, b_out, flag, out);
}

// Round 6
// 636.604 us; speedup vs baseline: 2.1769x; 2.1769x over previous
//
#include <hip/hip_runtime.h>
#include <math.h>

// B=8, Q=4096, C=256, H=8, D=32, L=4, P=4; levels 128/64/32/16 squared.
// Inputs fp32 (proven R1->R2), output fp32 (proven R4).
// ws layout (bytes): locs f32 @0 (33,554,432) | attn bf16 @33,554,432 (8,388,608)
//  | vbuf bf16 @41,943,040 (89,128,960: 8 batches x 21760 x 256)
//  | preb bf16 @131,072,000 (16,777,216) | wqT bf16[384][256] @147,849,216
//  | wv bf16[4][256][256] @148,045,824 | woT bf16[256][256] @148,570,112

typedef __attribute__((ext_vector_type(8))) short short8_t;
typedef __attribute__((ext_vector_type(4))) short short4_t;
typedef __attribute__((ext_vector_type(4))) float floatx4;

__device__ __forceinline__ float bf2f(unsigned short u) {
    return __uint_as_float(((unsigned int)u) << 16);
}
__device__ __forceinline__ unsigned short f2bf(float f) {
    unsigned int x = __float_as_uint(f);
    unsigned int r = x + 0x7fffu + ((x >> 16) & 1u);
    return (unsigned short)(r >> 16);
}

#define MFMA16(a, b, c) __builtin_amdgcn_mfma_f32_16x16x32_bf16((a), (b), (c), 0, 0, 0)
#define LPAD 40  // LDS row stride in shorts: 80 B = 16B-aligned frags, ~2-way banks (free)

// ---------------- K0: weight prep: cast + transpose to bf16
__global__ __launch_bounds__(256) void prep_kernel(
    const float* __restrict__ W_off, const float* __restrict__ W_attn,
    const float* __restrict__ Wv0, const float* __restrict__ Wv1,
    const float* __restrict__ Wv2, const float* __restrict__ Wv3,
    const float* __restrict__ W_out,
    unsigned short* __restrict__ wq,
    unsigned short* __restrict__ wv,
    unsigned short* __restrict__ wo)
{
    const int t = threadIdx.x;
    const int blk = blockIdx.x;
    if (blk < 40) {
        __shared__ float tile[64][65];
        int n0, c0, ncols, nbase;
        const float* src;
        unsigned short* dst;
        if (blk < 24) {
            int tt = blk; n0 = (tt >> 2) * 64; c0 = (tt & 3) * 64;
            if (n0 < 256) { src = W_off; ncols = 256; nbase = n0; }
            else          { src = W_attn; ncols = 128; nbase = n0 - 256; }
            dst = wq;
        } else {
            int tt = blk - 24; n0 = (tt >> 2) * 64; c0 = (tt & 3) * 64;
            src = W_out; ncols = 256; nbase = n0; dst = wo;
        }
        for (int i = 0; i < 4; ++i) {
            int idx = i * 256 + t; int c = idx >> 4, n4 = idx & 15;
            float4 v = *(const float4*)&src[(long)(c0 + c) * ncols + nbase + 4 * n4];
            tile[4 * n4 + 0][c] = v.x; tile[4 * n4 + 1][c] = v.y;
            tile[4 * n4 + 2][c] = v.z; tile[4 * n4 + 3][c] = v.w;
        }
        __syncthreads();
        for (int i = 0; i < 4; ++i) {
            int idx = i * 256 + t; int n = idx >> 4, cg = idx & 15;
            short4_t pk;
            pk[0] = (short)f2bf(tile[n][4 * cg + 0]);
            pk[1] = (short)f2bf(tile[n][4 * cg + 1]);
            pk[2] = (short)f2bf(tile[n][4 * cg + 2]);
            pk[3] = (short)f2bf(tile[n][4 * cg + 3]);
            *(short4_t*)&dst[(long)(n0 + n) * 256 + c0 + 4 * cg] = pk;
        }
    } else {
        long g0 = (long)(blk - 40) * 16384;
        for (int i = 0; i < 16; ++i) {
            long e = g0 + (long)(i * 256 + t) * 4;
            int l = (int)(e >> 16); int off = (int)(e & 65535);
            const float* s = (l == 0) ? Wv0 : (l == 1) ? Wv1 : (l == 2) ? Wv2 : Wv3;
            float4 v = *(const float4*)&s[off];
            short4_t pk;
            pk[0] = (short)f2bf(v.x); pk[1] = (short)f2bf(v.y);
            pk[2] = (short)f2bf(v.z); pk[3] = (short)f2bf(v.w);
            *(short4_t*)&wv[e] = pk;
        }
    }
}

// ---------------- K1: qproj MFMA. M=32768, N=384, K=256. Fused tanh->locs + softmax->attn.
__global__ __launch_bounds__(256) void qproj_mfma(
    const float* __restrict__ query, const float* __restrict__ refp,
    const unsigned short* __restrict__ wq,
    const float* __restrict__ b_off, const float* __restrict__ b_attn,
    float* __restrict__ locs, unsigned short* __restrict__ attn)
{
    __shared__ unsigned short aT[64 * LPAD];
    __shared__ unsigned short bT[384 * LPAD];
    const int t = threadIdx.x;
    const int r0 = blockIdx.x * 64;
    const int w = t >> 6, lane = t & 63, quad = lane >> 4, l15 = lane & 15;

    floatx4 acc[24];
#pragma unroll
    for (int i = 0; i < 24; ++i) acc[i] = (floatx4){0.f, 0.f, 0.f, 0.f};

    for (int k0 = 0; k0 < 256; k0 += 32) {
        __syncthreads();
        for (int i = 0; i < 2; ++i) {  // A: query 64x32 fp32 -> bf16 (512 float4)
            int idx = i * 256 + t; int row = idx >> 3, kq = idx & 7;
            float4 v = *(const float4*)&query[(long)(r0 + row) * 256 + k0 + 4 * kq];
            short4_t pk;
            pk[0] = (short)f2bf(v.x); pk[1] = (short)f2bf(v.y);
            pk[2] = (short)f2bf(v.z); pk[3] = (short)f2bf(v.w);
            *(short4_t*)&aT[row * LPAD + 4 * kq] = pk;
        }
        for (int i = 0; i < 6; ++i) {  // B: wqT 384x32 bf16 (1536 uint4)
            int idx = i * 256 + t; int n = idx >> 2, kq = idx & 3;
            uint4 v = *(const uint4*)&wq[(long)n * 256 + k0 + 8 * kq];
            *(uint4*)&bT[n * LPAD + 8 * kq] = v;
        }
        __syncthreads();
        short8_t a8 = *(const short8_t*)&aT[(16 * w + l15) * LPAD + 8 * quad];
#pragma unroll
        for (int j = 0; j < 24; ++j) {
            short8_t b8 = *(const short8_t*)&bT[(16 * j + l15) * LPAD + 8 * quad];
            acc[j] = MFMA16(a8, b8, acc[j]);
        }
    }

    const int rbase = r0 + 16 * w + 4 * quad;   // D row = quad*4 + reg
    float rx[4], ry[4];
#pragma unroll
    for (int g = 0; g < 4; ++g) {
        rx[g] = refp[(long)(rbase + g) * 2];
        ry[g] = refp[(long)(rbase + g) * 2 + 1];
    }
#pragma unroll
    for (int j = 0; j < 16; ++j) {  // offset cols n = h*32 + l*8 + p*2 + xy
        int n = 16 * j + l15;
        int h = n >> 5, l = (n >> 3) & 3, p = (n >> 1) & 3, xy = n & 1;
        float bias = b_off[n];
        float scale = 2.0f * (float)(1 << l);
        float dim1 = (float)((128 >> l) - 1);
#pragma unroll
        for (int g = 0; g < 4; ++g) {
            int r = rbase + g;
            float ref = xy ? ry[g] : rx[g];
            float px = ref * dim1 + tanhf(acc[j][g] + bias) * scale;
            locs[(((long)r * 8 + h) * 16 + l * 4 + p) * 2 + xy] = px;
        }
    }
#pragma unroll
    for (int j = 16; j < 24; ++j) {  // attn cols; softmax over 16 lanes of the tile
        int h = j - 16;
        float bias = b_attn[16 * h + l15];
#pragma unroll
        for (int g = 0; g < 4; ++g) {
            float v = acc[j][g] + bias;
            float m = v;
            m = fmaxf(m, __shfl_xor(m, 1)); m = fmaxf(m, __shfl_xor(m, 2));
            m = fmaxf(m, __shfl_xor(m, 4)); m = fmaxf(m, __shfl_xor(m, 8));
            float e = __expf(v - m);
            float s = e;
            s += __shfl_xor(s, 1); s += __shfl_xor(s, 2);
            s += __shfl_xor(s, 4); s += __shfl_xor(s, 8);
            attn[((long)(rbase + g) * 8 + h) * 16 + l15] = f2bf(e / s);
        }
    }
}

// ---------------- K2: vproj MFMA. Block tile 128o x 64s; D[o][s] = Wv[o][c]*feat[c][s]+bv
__global__ __launch_bounds__(256) void vproj_mfma(
    const float* __restrict__ feat0, const float* __restrict__ feat1,
    const float* __restrict__ feat2, const float* __restrict__ feat3,
    const unsigned short* __restrict__ wv,
    const float* __restrict__ bv0, const float* __restrict__ bv1,
    const float* __restrict__ bv2, const float* __restrict__ bv3,
    unsigned short* __restrict__ vbuf)
{
    __shared__ unsigned short aW[128 * LPAD];
    __shared__ unsigned short bF[64 * LPAD];
    const int blk = blockIdx.x;
    const int b = blk / 680;
    const int r = blk % 680;
    const float* feat; const unsigned short* wvl; const float* bvl; int S; long loff; int til;
    if (r < 512)      { til = r;       feat = feat0; wvl = wv;          bvl = bv0; S = 16384; loff = 0; }
    else if (r < 640) { til = r - 512; feat = feat1; wvl = wv + 65536;  bvl = bv1; S = 4096;  loff = 4194304; }
    else if (r < 672) { til = r - 640; feat = feat2; wvl = wv + 131072; bvl = bv2; S = 1024;  loff = 5242880; }
    else              { til = r - 672; feat = feat3; wvl = wv + 196608; bvl = bv3; S = 256;   loff = 5505024; }
    const int s0 = (til >> 1) * 64;
    const int o0 = (til & 1) * 128;
    const long fb = (long)b * 256 * S;
    const int t = threadIdx.x;
    const int w = t >> 6, lane = t & 63, quad = lane >> 4, l15 = lane & 15;

    floatx4 acc[2][4];
#pragma unroll
    for (int i = 0; i < 2; ++i)
#pragma unroll
        for (int j = 0; j < 4; ++j) acc[i][j] = (floatx4){0.f, 0.f, 0.f, 0.f};

    for (int k0 = 0; k0 < 256; k0 += 32) {
        __syncthreads();
        for (int i = 0; i < 2; ++i) {  // A: Wv 128 rows x 32k = 512 uint4  [R5 FIX]
            int idx = i * 256 + t; int o = idx >> 2, kq = idx & 3;
            uint4 v = *(const uint4*)&wvl[(long)(o0 + o) * 256 + k0 + 8 * kq];
            *(uint4*)&aW[o * LPAD + 8 * kq] = v;
        }
        for (int i = 0; i < 8; ++i) {  // B: feat[k][s] -> LDS [s][c] (transpose)
            int idx = i * 256 + t; int s = idx & 63, c = idx >> 6;
            float v = feat[fb + (long)(k0 + c) * S + s0 + s];
            bF[s * LPAD + c] = f2bf(v);
        }
        __syncthreads();
        short8_t am0 = *(const short8_t*)&aW[(32 * w + l15) * LPAD + 8 * quad];
        short8_t am1 = *(const short8_t*)&aW[(32 * w + 16 + l15) * LPAD + 8 * quad];
#pragma unroll
        for (int j = 0; j < 4; ++j) {
            short8_t b8 = *(const short8_t*)&bF[(16 * j + l15) * LPAD + 8 * quad];
            acc[0][j] = MFMA16(am0, b8, acc[0][j]);
            acc[1][j] = MFMA16(am1, b8, acc[1][j]);
        }
    }

    unsigned short* vb = vbuf + (long)b * 5570560 + loff;
#pragma unroll
    for (int i = 0; i < 2; ++i) {
        int obase = o0 + 32 * w + 16 * i + 4 * quad;
        float4 bias = *(const float4*)&bvl[obase];
#pragma unroll
        for (int j = 0; j < 4; ++j) {
            int s = s0 + 16 * j + l15;
            short4_t pk;
            pk[0] = (short)f2bf(acc[i][j][0] + bias.x);
            pk[1] = (short)f2bf(acc[i][j][1] + bias.y);
            pk[2] = (short)f2bf(acc[i][j][2] + bias.z);
            pk[3] = (short)f2bf(acc[i][j][3] + bias.w);
            *(short4_t*)&vb[(long)s * 256 + obase] = pk;
        }
    }
}

// ---------------- K3: bilinear sampling + attn accumulate. pre -> bf16 ws.
__global__ __launch_bounds__(256) void sample_kernel(
    const float* __restrict__ locs,
    const unsigned short* __restrict__ attn,
    const unsigned short* __restrict__ vbuf,
    unsigned short* __restrict__ preb)
{
    const int r = blockIdx.x;
    const int b = r >> 12;
    const int t = threadIdx.x;
    const int h = t >> 5, d = t & 31;
    const long loff[4] = {0, 4194304, 5242880, 5505024};

    const float* lpb = locs + ((long)r * 8 + h) * 32;
    const unsigned short* apb = attn + ((long)r * 8 + h) * 16;
    const unsigned short* vbb = vbuf + (long)b * 5570560;
    float o = 0.f;
#pragma unroll
    for (int l = 0; l < 4; ++l) {
        const int Wl = 128 >> l;
        const unsigned short* V = vbb + loff[l] + h * 32 + d;
#pragma unroll
        for (int p = 0; p < 4; ++p) {
            const int k = l * 4 + p;
            const float px = lpb[k * 2], py = lpb[k * 2 + 1];
            const float a = bf2f(apb[k]);
            const float fx = floorf(px), fy = floorf(py);
            const int x0 = (int)fx, y0 = (int)fy;
            const int x1 = x0 + 1, y1 = y0 + 1;
            const float wx = px - fx, wy = py - fy;
            const bool vx0 = (x0 >= 0) && (x0 < Wl), vx1 = (x1 >= 0) && (x1 < Wl);
            const bool vy0 = (y0 >= 0) && (y0 < Wl), vy1 = (y1 >= 0) && (y1 < Wl);
            const int cx0 = min(max(x0, 0), Wl - 1), cx1 = min(max(x1, 0), Wl - 1);
            const int cy0 = min(max(y0, 0), Wl - 1), cy1 = min(max(y1, 0), Wl - 1);
            const float g00 = bf2f(V[(long)(cy0 * Wl + cx0) * 256]);
            const float g01 = bf2f(V[(long)(cy0 * Wl + cx1) * 256]);
            const float g10 = bf2f(V[(long)(cy1 * Wl + cx0) * 256]);
            const float g11 = bf2f(V[(long)(cy1 * Wl + cx1) * 256]);
            const float w00 = (1.f - wx) * (1.f - wy) * ((vx0 && vy0) ? 1.f : 0.f);
            const float w01 = wx * (1.f - wy) * ((vx1 && vy0) ? 1.f : 0.f);
            const float w10 = (1.f - wx) * wy * ((vx0 && vy1) ? 1.f : 0.f);
            const float w11 = wx * wy * ((vx1 && vy1) ? 1.f : 0.f);
            o += a * (g00 * w00 + g01 * w01 + g10 * w10 + g11 * w11);
        }
    }
    preb[(long)r * 256 + t] = f2bf(o);
}

// ---------------- K4: outproj MFMA. D[j][r]; coalesced float4 stores.
__global__ __launch_bounds__(256) void outproj_mfma(
    const unsigned short* __restrict__ preb,
    const unsigned short* __restrict__ wo,
    const float* __restrict__ b_out,
    float* __restrict__ out)
{
    __shared__ unsigned short aJ[256 * LPAD];
    __shared__ unsigned short bR[64 * LPAD];
    const int t = threadIdx.x;
    const int r0 = blockIdx.x * 64;
    const int w = t >> 6, lane = t & 63, quad = lane >> 4, l15 = lane & 15;

    floatx4 acc[4][4];
#pragma unroll
    for (int i = 0; i < 4; ++i)
#pragma unroll
        for (int j = 0; j < 4; ++j) acc[i][j] = (floatx4){0.f, 0.f, 0.f, 0.f};

    for (int k0 = 0; k0 < 256; k0 += 32) {
        __syncthreads();
        for (int i = 0; i < 4; ++i) {  // A: woT 256 rows x 32k = 1024 uint4  [R5 FIX]
            int idx = i * 256 + t; int j = idx >> 2, kq = idx & 3;
            uint4 v = *(const uint4*)&wo[(long)j * 256 + k0 + 8 * kq];
            *(uint4*)&aJ[j * LPAD + 8 * kq] = v;
        }
        {   // B: preb 64 rows x 32k = 256 uint4  [R5 FIX]
            int rr = t >> 2, kq = t & 3;
            uint4 v = *(const uint4*)&preb[(long)(r0 + rr) * 256 + k0 + 8 * kq];
            *(uint4*)&bR[rr * LPAD + 8 * kq] = v;
        }
        __syncthreads();
        short8_t am[4];
#pragma unroll
        for (int mi = 0; mi < 4; ++mi)
            am[mi] = *(const short8_t*)&aJ[(64 * w + 16 * mi + l15) * LPAD + 8 * quad];
#pragma unroll
        for (int nj = 0; nj < 4; ++nj) {
            short8_t b8 = *(const short8_t*)&bR[(16 * nj + l15) * LPAD + 8 * quad];
#pragma unroll
            for (int mi = 0; mi < 4; ++mi)
                acc[mi][nj] = MFMA16(am[mi], b8, acc[mi][nj]);
        }
    }

#pragma unroll
    for (int mi = 0; mi < 4; ++mi) {
        int j0 = 64 * w + 16 * mi + 4 * quad;
        float4 bias = *(const float4*)&b_out[j0];
#pragma unroll
        for (int nj = 0; nj < 4; ++nj) {
            int r = r0 + 16 * nj + l15;
            float4 res;
            res.x = acc[mi][nj][0] + bias.x;
            res.y = acc[mi][nj][1] + bias.y;
            res.z = acc[mi][nj][2] + bias.z;
            res.w = acc[mi][nj][3] + bias.w;
            *(float4*)&out[(long)r * 256 + j0] = res;
        }
    }
}

extern "C" void kernel_launch(void* const* d_in, const int* in_sizes, int n_in,
                              void* d_out, int out_size, void* d_ws, size_t ws_size,
                              hipStream_t stream) {
    const float* query  = (const float*)d_in[0];
    const float* refp   = (const float*)d_in[1];
    const float* feat0  = (const float*)d_in[2];
    const float* feat1  = (const float*)d_in[3];
    const float* feat2  = (const float*)d_in[4];
    const float* feat3  = (const float*)d_in[5];
    const float* W_off  = (const float*)d_in[6];
    const float* b_off  = (const float*)d_in[7];
    const float* W_attn = (const float*)d_in[8];
    const float* b_attn = (const float*)d_in[9];
    const float* Wv0 = (const float*)d_in[10]; const float* bv0 = (const float*)d_in[11];
    const float* Wv1 = (const float*)d_in[12]; const float* bv1 = (const float*)d_in[13];
    const float* Wv2 = (const float*)d_in[14]; const float* bv2 = (const float*)d_in[15];
    const float* Wv3 = (const float*)d_in[16]; const float* bv3 = (const float*)d_in[17];
    const float* W_out = (const float*)d_in[18]; const float* b_out = (const float*)d_in[19];
    float* out = (float*)d_out;

    char* ws = (char*)d_ws;
    float*          locs = (float*)(ws + 0);
    unsigned short* attn = (unsigned short*)(ws + 33554432);
    unsigned short* vbuf = (unsigned short*)(ws + 41943040);
    unsigned short* preb = (unsigned short*)(ws + 131072000);
    unsigned short* wq   = (unsigned short*)(ws + 147849216);
    unsigned short* wv   = (unsigned short*)(ws + 148045824);
    unsigned short* wo   = (unsigned short*)(ws + 148570112);

    prep_kernel<<<56, 256, 0, stream>>>(W_off, W_attn, Wv0, Wv1, Wv2, Wv3, W_out,
                                        wq, wv, wo);
    qproj_mfma<<<512, 256, 0, stream>>>(query, refp, wq, b_off, b_attn, locs, attn);
    vproj_mfma<<<5440, 256, 0, stream>>>(feat0, feat1, feat2, feat3, wv,
                                         bv0, bv1, bv2, bv3, vbuf);
    sample_kernel<<<32768, 256, 0, stream>>>(locs, attn, vbuf, preb);
    outproj_mfma<<<512, 256, 0, stream>>>(preb, wo, b_out, out);
}